// Round 16
// baseline (153.856 us; speedup 1.0000x reference)
//
#include <hip/hip_runtime.h>
#include <hip/hip_bf16.h>
#include <math.h>

#define S_LEN 2048
#define HID 2048
#define NH 32
#define NKV 8
#define HD 64
#define WINDOW 1024
#define QBLK 256
#define QKVN 3072   // fused Q(2048) | K(512) | V(512) columns

typedef __attribute__((ext_vector_type(8))) short bx8;          // 8 bf16 (4 VGPRs) — MFMA A/B frag
typedef __attribute__((ext_vector_type(4))) float fx4;          // MFMA C/D frag
typedef __attribute__((ext_vector_type(8))) unsigned short us8; // 8 bf16 raw

#define GL_LDS16(gp, lp) \
    __builtin_amdgcn_global_load_lds((__attribute__((address_space(1))) const void*)(gp), \
                                     (__attribute__((address_space(3))) void*)(lp), 16, 0, 0)

// ---------------- prep: rope tables + hs conv + 4 weight transposes, ONE dispatch ----------------
__global__ __launch_bounds__(256) void prep_kernel(const float* __restrict__ hs,
                                                   const float* __restrict__ Wq,
                                                   const float* __restrict__ Wk,
                                                   const float* __restrict__ Wv,
                                                   const float* __restrict__ Wo,
                                                   float* __restrict__ cosT, float* __restrict__ sinT,
                                                   __hip_bfloat16* __restrict__ hsb,
                                                   __hip_bfloat16* __restrict__ WqkvT,
                                                   __hip_bfloat16* __restrict__ WoT) {
    __shared__ float tile[32][33];
    int b = blockIdx.x, t = threadIdx.x;
    if (b < 256) {
        int idx = b * 256 + t;           // s*32 + f
        int s = idx >> 5, f = idx & 31;
        double inv = exp(-2.0 * (double)f / 64.0 * log(500000.0));
        double ang = (double)s * inv;
        cosT[idx] = (float)cos(ang);
        sinT[idx] = (float)sin(ang);
        return;
    }
    b -= 256;
    if (b < 2048) {
        int i = (b * 256 + t) * 8;
        float4 a = *reinterpret_cast<const float4*>(&hs[i]);
        float4 c = *reinterpret_cast<const float4*>(&hs[i + 4]);
        __hip_bfloat16 o[8] __attribute__((aligned(16)));
        o[0] = __float2bfloat16(a.x); o[1] = __float2bfloat16(a.y);
        o[2] = __float2bfloat16(a.z); o[3] = __float2bfloat16(a.w);
        o[4] = __float2bfloat16(c.x); o[5] = __float2bfloat16(c.y);
        o[6] = __float2bfloat16(c.z); o[7] = __float2bfloat16(c.w);
        *reinterpret_cast<bx8*>(&hsb[i]) = *reinterpret_cast<bx8*>(o);
        return;
    }
    b -= 2048;
    const float* src; __hip_bfloat16* dst; int Nd, bx, by;
    if (b < 4096)      { src = Wq; dst = WqkvT;                        Nd = 2048; bx = b & 63; by = b >> 6; }
    else if (b < 5120) { b -= 4096; src = Wk; dst = WqkvT + (size_t)2048 * 2048; Nd = 512; bx = b & 15; by = b >> 4; }
    else if (b < 6144) { b -= 5120; src = Wv; dst = WqkvT + (size_t)2560 * 2048; Nd = 512; bx = b & 15; by = b >> 4; }
    else               { b -= 6144; src = Wo; dst = WoT;               Nd = 2048; bx = b & 63; by = b >> 6; }
    int n0 = bx * 32, k0 = by * 32, tx = t & 31, ty = t >> 5;  // 32 x 8
#pragma unroll
    for (int i = 0; i < 4; i++)
        tile[ty + 8 * i][tx] = src[(size_t)(k0 + ty + 8 * i) * Nd + n0 + tx];
    __syncthreads();
#pragma unroll
    for (int i = 0; i < 4; i++)
        dst[(size_t)(n0 + ty + 8 * i) * 2048 + k0 + tx] = __float2bfloat16(tile[tx][ty + 8 * i]);
}

// ---------------- rope (Q+K) + vtrans, ONE dispatch ----------------
__global__ __launch_bounds__(256) void ropev_kernel(__hip_bfloat16* __restrict__ QKV,
                                                    __hip_bfloat16* __restrict__ Vt,
                                                    const float* __restrict__ cosT,
                                                    const float* __restrict__ sinT) {
    __shared__ __hip_bfloat16 tile[32][33];
    int b = blockIdx.x, t = threadIdx.x;
    if (b < 10240) {
        int idx = b * 256 + t;           // s*(40*32) + head*32 + f
        int f = idx & 31;
        int head = (idx >> 5) % (NH + NKV);
        int s = idx / ((NH + NKV) * 32);
        float c  = cosT[(s << 5) + f];
        float sn = sinT[(s << 5) + f];
        __hip_bfloat16* p = (head < NH) ? (QKV + (size_t)s * QKVN + head * HD)
                                        : (QKV + (size_t)s * QKVN + 2048 + (head - NH) * HD);
        float x1 = __bfloat162float(p[f]), x2 = __bfloat162float(p[f + 32]);
        p[f]      = __float2bfloat16(x1 * c - x2 * sn);
        p[f + 32] = __float2bfloat16(x2 * c + x1 * sn);
        return;
    }
    b -= 10240;
    int s0 = (b & 63) * 32, d0 = (b >> 6) * 32;
    int tx = t & 31, ty = t >> 5;  // 32 x 8
#pragma unroll
    for (int i = 0; i < 4; i++)
        tile[ty + 8 * i][tx] = QKV[(size_t)(s0 + ty + 8 * i) * QKVN + 2560 + d0 + tx];
    __syncthreads();
#pragma unroll
    for (int i = 0; i < 4; i++)
        Vt[(size_t)(d0 + ty + 8 * i) * S_LEN + s0 + tx] = tile[tx][ty + 8 * i];
}

// ---------------- pipelined bf16 MFMA GEMM, 64x128 tile, XCD N-striped (frozen R14) ----------------
template <int OUTBF16>
__global__ __launch_bounds__(256) void gemm_pipe_kernel(const __hip_bfloat16* __restrict__ A,
                                                        const __hip_bfloat16* __restrict__ Bt,
                                                        void* __restrict__ Cp,
                                                        int M, int N, int K, int stripe) {
    __shared__ __hip_bfloat16 As[3][2048];   // 3 x [64 rows][32 k]
    __shared__ __hip_bfloat16 Bs[3][4096];   // 3 x [128 rows][32 k]

    const int bid = blockIdx.x;
    const int x = bid & 7, j = bid >> 3;
    const int bn = (x * stripe + j % stripe) * 128;
    const int bm = (j / stripe) * 64;

    const int t = threadIdx.x, w = t >> 6, l = t & 63;
    const int wr = (w >> 1) * 32, wc = (w & 1) * 64;
    const int lr = l & 15;
    const int rdslot = (((l >> 4) ^ ((lr >> 1) & 3))) * 8;
    const int srow = w * 16 + (l >> 2);
    const int scol = (((l & 3) ^ ((l >> 3) & 3))) * 8;
    const int ldsoff = w * 512;

    const __hip_bfloat16* ga0 = A + (size_t)(bm + srow) * K + scol;
    const __hip_bfloat16* gb0 = Bt + (size_t)(bn + srow) * K + scol;
    const size_t half = (size_t)64 * K;

    fx4 acc[2][4];
#pragma unroll
    for (int m = 0; m < 2; m++)
#pragma unroll
        for (int n = 0; n < 4; n++) acc[m][n] = (fx4){0.f, 0.f, 0.f, 0.f};

    const int T = K >> 5;

#define STAGE(kt, b)                                              \
    do {                                                          \
        const __hip_bfloat16* ga = ga0 + (kt) * 32;               \
        const __hip_bfloat16* gb = gb0 + (kt) * 32;               \
        GL_LDS16(ga,        &As[(b)][ldsoff]);                    \
        GL_LDS16(gb,        &Bs[(b)][ldsoff]);                    \
        GL_LDS16(gb + half, &Bs[(b)][2048 + ldsoff]);             \
    } while (0)

    STAGE(0, 0);
    STAGE(1, 1);

    for (int i = 0; i < T; i++) {
        const int r = i % 3;
        if (i + 1 < T) asm volatile("s_waitcnt vmcnt(3)" ::: "memory");
        else           asm volatile("s_waitcnt vmcnt(0)" ::: "memory");
        __builtin_amdgcn_s_barrier();
        asm volatile("" ::: "memory");
        if (i + 2 < T) STAGE(i + 2, (i + 2) % 3);

        bx8 af[2], bf[4];
#pragma unroll
        for (int m = 0; m < 2; m++)
            af[m] = *reinterpret_cast<const bx8*>(&As[r][(wr + m * 16 + lr) * 32 + rdslot]);
#pragma unroll
        for (int n = 0; n < 4; n++)
            bf[n] = *reinterpret_cast<const bx8*>(&Bs[r][(wc + n * 16 + lr) * 32 + rdslot]);
#pragma unroll
        for (int m = 0; m < 2; m++)
#pragma unroll
            for (int n = 0; n < 4; n++)
                acc[m][n] = __builtin_amdgcn_mfma_f32_16x16x32_bf16(af[m], bf[n], acc[m][n], 0, 0, 0);
    }
#undef STAGE

    const int lq = (l >> 4) * 4;
#pragma unroll
    for (int m = 0; m < 2; m++)
#pragma unroll
        for (int n = 0; n < 4; n++)
#pragma unroll
            for (int r2 = 0; r2 < 4; r2++) {
                int row = bm + wr + m * 16 + lq + r2;
                int col = bn + wc + n * 16 + lr;
                float v = acc[m][n][r2];
                if (OUTBF16)
                    ((__hip_bfloat16*)Cp)[(size_t)row * N + col] = __float2bfloat16(v);
                else
                    ((float*)Cp)[(size_t)row * N + col] = v;
            }
}

// ---------------- MFMA sliding-window flash attention, swapped-operand softmax ----------------
// R16: QBLK=256, 8 waves x 32 q-rows (2 m-frags/wave). kb/vb fragment reads and
// K/V staging shared across both m-frags; two independent softmax chains per
// wave give intra-wave ILP. Staging/epilogue per R15 (gl_lds + single barrier).
__global__ __launch_bounds__(512, 2) void attn_kernel(const __hip_bfloat16* __restrict__ Q,
                                                      const __hip_bfloat16* __restrict__ Kg,
                                                      const __hip_bfloat16* __restrict__ Vtg,
                                                      __hip_bfloat16* __restrict__ Ab) {
    __shared__ __hip_bfloat16 Ks[2][4096];
    __shared__ __hip_bfloat16 Vs[2][4096];
    __shared__ __hip_bfloat16 Ps[QBLK * 64];   // 32KB

    // 256 blocks: each XCD gets 32 consecutive swz = 4 consecutive heads
    const int bid = blockIdx.x;
    const int swz = (bid & 7) * 32 + (bid >> 3);
    const int h = swz >> 3, qi = swz & 7;
    const int qb = qi * QBLK;
    const int kvh = h >> 2;

    const int t = threadIdx.x, w = t >> 6, l = t & 63;
    const int lr = l & 15, g = l >> 4, lk = g * 8;
    const int qbw = qb + 32 * w;      // this wave's 32 q-rows

    char* PsB = (char*)Ps;

    // hoisted Q fragments (B-operand; lane holds q-row per m-frag)
    bx8 qa[2][2];
#pragma unroll
    for (int mf = 0; mf < 2; mf++)
#pragma unroll
        for (int ks = 0; ks < 2; ks++)
            qa[mf][ks] = *reinterpret_cast<const bx8*>(
                &Q[(size_t)(qbw + 16 * mf + lr) * QKVN + h * HD + ks * 32 + lk]);

    fx4 ot[2][4];
    float mrow[2], srow[2];
#pragma unroll
    for (int mf = 0; mf < 2; mf++) {
        mrow[mf] = -1e30f; srow[mf] = 0.f;
#pragma unroll
        for (int n = 0; n < 4; n++) ot[mf][n] = (fx4){0.f, 0.f, 0.f, 0.f};
    }

    const int k0_first = (qb >= 1024) ? (qb - 1024) : 0;
    const int k0_last  = qb + 192;            // last tile containing row qb+255
    const int wmax = qbw + 31;

    // staging: thread t covers row sr=t>>3, 16B chunk c8=t&7; linear LDS dst +
    // pre-swizzled global src (content[sr][c] = global[sr][c ^ (sr&7)])
    const int sr = t >> 3, c8 = t & 7;
    const int scolsw = 8 * (c8 ^ (sr & 7));
    const int kcol = kvh * HD + scolsw;
    const int vrow = kvh * HD + sr;
    __hip_bfloat16* ldsK = &Ks[0][0] + (t >> 6) * 512;
    __hip_bfloat16* ldsV = &Vs[0][0] + (t >> 6) * 512;

#define ASTAGE(k0v, p)                                                           \
    do {                                                                         \
        GL_LDS16(&Kg[(size_t)((k0v) + sr) * QKVN + kcol], ldsK + (p) * 4096);    \
        GL_LDS16(&Vtg[(size_t)vrow * S_LEN + (k0v) + scolsw], ldsV + (p) * 4096);\
    } while (0)

    ASTAGE(k0_first, 0);

    int ti = 0;
    for (int k0 = k0_first; k0 <= k0_last; k0 += 64, ++ti) {
        const int p = ti & 1;
        asm volatile("s_waitcnt vmcnt(0)" ::: "memory");
        __builtin_amdgcn_s_barrier();
        asm volatile("" ::: "memory");
        if (k0 + 64 <= k0_last) ASTAGE(k0 + 64, p ^ 1);

        if (k0 <= wmax) {
            char* KsB = (char*)&Ks[p][0];
            char* VsB = (char*)&Vs[p][0];
            // K fragments (A-operand: rows = keys) — shared by both m-frags
            bx8 kb[4][2];
#pragma unroll
            for (int n = 0; n < 4; n++)
#pragma unroll
                for (int ks = 0; ks < 2; ks++) {
                    int row = 16 * n + lr;
                    kb[n][ks] = *reinterpret_cast<const bx8*>(
                        KsB + row * 128 + (((ks * 64) + 16 * g) ^ ((row & 7) << 4)));
                }
#pragma unroll
            for (int mf = 0; mf < 2; mf++) {
                const int rowq = qbw + 16 * mf + lr;
                const int prow = 32 * w + 16 * mf + lr;
                const int psz = (prow & 7) << 4;
                // S^T = K · Q^T : rows=keys (16n+4g+r), cols=q (lr)
                fx4 sc[4];
#pragma unroll
                for (int n = 0; n < 4; n++) {
                    sc[n] = __builtin_amdgcn_mfma_f32_16x16x32_bf16(kb[n][0], qa[mf][0],
                                                                    (fx4){0.f, 0.f, 0.f, 0.f}, 0, 0, 0);
                    sc[n] = __builtin_amdgcn_mfma_f32_16x16x32_bf16(kb[n][1], qa[mf][1], sc[n], 0, 0, 0);
                }
                // scale + sliding-window mask (interior tiles skip the mask)
                const int qlow = qbw + 16 * mf;
                const bool interior = (k0 + 63 <= qlow) && (k0 >= qlow - 1008);
                if (interior) {
#pragma unroll
                    for (int n = 0; n < 4; n++)
#pragma unroll
                        for (int r = 0; r < 4; r++) sc[n][r] *= 0.125f;
                } else {
#pragma unroll
                    for (int n = 0; n < 4; n++)
#pragma unroll
                        for (int r = 0; r < 4; r++) {
                            int key = k0 + 16 * n + 4 * g + r;
                            bool valid = (key <= rowq) && (key >= rowq - (WINDOW - 1));
                            sc[n][r] = valid ? sc[n][r] * 0.125f : -1e30f;
                        }
                }
                // in-register row max
                float tmax = fmaxf(fmaxf(sc[0][0], sc[0][1]), fmaxf(sc[0][2], sc[0][3]));
#pragma unroll
                for (int n = 1; n < 4; n++)
                    tmax = fmaxf(tmax, fmaxf(fmaxf(sc[n][0], sc[n][1]), fmaxf(sc[n][2], sc[n][3])));
                tmax = fmaxf(tmax, __shfl_xor(tmax, 16));
                tmax = fmaxf(tmax, __shfl_xor(tmax, 32));
                float mn = fmaxf(mrow[mf], tmax);
                float fs = __expf(mrow[mf] - mn);
                mrow[mf] = mn;
                // exp + P^T write (packed b64, lane's own row) + sum
                float ps = 0.f;
#pragma unroll
                for (int n = 0; n < 4; n++) {
#pragma unroll
                    for (int r = 0; r < 4; r++) {
                        float p2 = __expf(sc[n][r] - mn);
                        sc[n][r] = p2;
                        ps += p2;
                    }
                    __hip_bfloat16 pk[4] __attribute__((aligned(8)));
                    pk[0] = __float2bfloat16(sc[n][0]); pk[1] = __float2bfloat16(sc[n][1]);
                    pk[2] = __float2bfloat16(sc[n][2]); pk[3] = __float2bfloat16(sc[n][3]);
                    *reinterpret_cast<unsigned long long*>(PsB + prow * 128 + ((32 * n + 8 * g) ^ psz)) =
                        *reinterpret_cast<unsigned long long*>(pk);
                }
                ps += __shfl_xor(ps, 16);
                ps += __shfl_xor(ps, 32);
                srow[mf] = srow[mf] * fs + ps;
#pragma unroll
                for (int n = 0; n < 4; n++)
#pragma unroll
                    for (int r = 0; r < 4; r++) ot[mf][n][r] *= fs;
            }
            // V fragments (A-operand: rows = d) — shared by both m-frags
            bx8 vb[4][2];
#pragma unroll
            for (int n = 0; n < 4; n++)
#pragma unroll
                for (int ks = 0; ks < 2; ks++) {
                    int row = 16 * n + lr;
                    vb[n][ks] = *reinterpret_cast<const bx8*>(
                        VsB + row * 128 + (((ks * 64) + 16 * g) ^ ((row & 7) << 4)));
                }
#pragma unroll
            for (int mf = 0; mf < 2; mf++) {
                const int prow = 32 * w + 16 * mf + lr;
                const int psz = (prow & 7) << 4;
                bx8 pb[2];
#pragma unroll
                for (int ks = 0; ks < 2; ks++)
                    pb[ks] = *reinterpret_cast<const bx8*>(
                        PsB + prow * 128 + (((ks * 64) + 16 * g) ^ psz));
                // O^T += V^T · P : rows=d (16n+4g+r), cols=q (lr)
#pragma unroll
                for (int n = 0; n < 4; n++) {
                    ot[mf][n] = __builtin_amdgcn_mfma_f32_16x16x32_bf16(vb[n][0], pb[0], ot[mf][n], 0, 0, 0);
                    ot[mf][n] = __builtin_amdgcn_mfma_f32_16x16x32_bf16(vb[n][1], pb[1], ot[mf][n], 0, 0, 0);
                }
            }
        }
    }
#undef ASTAGE

    // ---- epilogue: normalize, O^T frags -> Ps as [q][d] (b64+XOR), then
    // cooperative coalesced row-major store to Ab (256 rows x 8 chunks) ----
#pragma unroll
    for (int mf = 0; mf < 2; mf++) {
        const int prow = 32 * w + 16 * mf + lr;
        const int psz = (prow & 7) << 4;
        const float inv = 1.f / srow[mf];
#pragma unroll
        for (int n = 0; n < 4; n++) {
            __hip_bfloat16 pk[4] __attribute__((aligned(8)));
#pragma unroll
            for (int r = 0; r < 4; r++) pk[r] = __float2bfloat16(ot[mf][n][r] * inv);
            *reinterpret_cast<unsigned long long*>(PsB + prow * 128 + ((32 * n + 8 * g) ^ psz)) =
                *reinterpret_cast<unsigned long long*>(pk);
        }
    }
    __syncthreads();
#pragma unroll
    for (int j = 0; j < 4; j++) {
        const int row = (t >> 3) + 64 * j, c = t & 7;   // 256 rows x 8 us8-chunks
        us8 v = *reinterpret_cast<const us8*>(PsB + row * 128 + ((c * 16) ^ ((row & 7) << 4)));
        *reinterpret_cast<us8*>(&Ab[(size_t)(qb + row) * HID + h * HD + c * 8]) = v;
    }
}

extern "C" void kernel_launch(void* const* d_in, const int* in_sizes, int n_in,
                              void* d_out, int out_size, void* d_ws, size_t ws_size,
                              hipStream_t stream) {
    const float* hs = (const float*)d_in[0];
    const float* Wq = (const float*)d_in[1];
    const float* Wk = (const float*)d_in[2];
    const float* Wv = (const float*)d_in[3];
    const float* Wo = (const float*)d_in[4];

    float* ws   = (float*)d_ws;
    float* cosT = ws;                  // 65536 f32
    float* sinT = cosT + 65536;        // 65536 f32
    __hip_bfloat16* hsb    = (__hip_bfloat16*)(sinT + 65536);   // [2048][2048]
    __hip_bfloat16* WqkvT  = hsb + 4194304;                     // [3072][2048]: Wq|Wk|Wv rows
    __hip_bfloat16* WoT    = WqkvT + 6291456;                   // [2048][2048]
    __hip_bfloat16* QKVb   = WoT + 4194304;                     // [2048][3072]
    __hip_bfloat16* Vt     = QKVb + 6291456;                    // [512][2048]
    __hip_bfloat16* Ab     = hsb;                               // alias: hsb dead after QKV gemm

    // prep: tables + hs->bf16 + weight transposes (one dispatch)
    prep_kernel<<<12544, 256, 0, stream>>>(hs, Wq, Wk, Wv, Wo, cosT, sinT, hsb, WqkvT, WoT);

    // fused QKV projection (64x128 tiles, 768 blocks, XCD stripe=3)
    gemm_pipe_kernel<1><<<768, 256, 0, stream>>>(hsb, WqkvT, QKVb, 2048, QKVN, 2048, 3);

    // RoPE (Q+K) + V transpose (one dispatch)
    ropev_kernel<<<11264, 256, 0, stream>>>(QKVb, Vt, cosT, sinT);

    // attention: 256-row blocks, 8 waves x 32 rows, writes row-major Ab directly
    attn_kernel<<<256, 512, 0, stream>>>(QKVb, QKVb + 2048, Vt, Ab);

    // output projection (64x128 tiles, 512 blocks, XCD stripe=2)
    gemm_pipe_kernel<0><<<512, 256, 0, stream>>>(Ab, WoT, d_out, 2048, 2048, 2048, 2);
}

// Round 17
// 144.460 us; speedup vs baseline: 1.0650x; 1.0650x over previous
//
#include <hip/hip_runtime.h>
#include <hip/hip_bf16.h>
#include <math.h>

#define S_LEN 2048
#define HID 2048
#define NH 32
#define NKV 8
#define HD 64
#define WINDOW 1024
#define QBLK 128
#define QKVN 3072   // fused Q(2048) | K(512) | V(512) columns

typedef __attribute__((ext_vector_type(8))) short bx8;          // 8 bf16 (4 VGPRs) — MFMA A/B frag
typedef __attribute__((ext_vector_type(4))) float fx4;          // MFMA C/D frag
typedef __attribute__((ext_vector_type(8))) unsigned short us8; // 8 bf16 raw

#define GL_LDS16(gp, lp) \
    __builtin_amdgcn_global_load_lds((__attribute__((address_space(1))) const void*)(gp), \
                                     (__attribute__((address_space(3))) void*)(lp), 16, 0, 0)

// ---------------- prep: rope tables + hs conv + 4 weight transposes, ONE dispatch ----------------
__global__ __launch_bounds__(256) void prep_kernel(const float* __restrict__ hs,
                                                   const float* __restrict__ Wq,
                                                   const float* __restrict__ Wk,
                                                   const float* __restrict__ Wv,
                                                   const float* __restrict__ Wo,
                                                   float* __restrict__ cosT, float* __restrict__ sinT,
                                                   __hip_bfloat16* __restrict__ hsb,
                                                   __hip_bfloat16* __restrict__ WqkvT,
                                                   __hip_bfloat16* __restrict__ WoT) {
    __shared__ float tile[32][33];
    int b = blockIdx.x, t = threadIdx.x;
    if (b < 256) {
        int idx = b * 256 + t;           // s*32 + f
        int s = idx >> 5, f = idx & 31;
        double inv = exp(-2.0 * (double)f / 64.0 * log(500000.0));
        double ang = (double)s * inv;
        cosT[idx] = (float)cos(ang);
        sinT[idx] = (float)sin(ang);
        return;
    }
    b -= 256;
    if (b < 2048) {
        int i = (b * 256 + t) * 8;
        float4 a = *reinterpret_cast<const float4*>(&hs[i]);
        float4 c = *reinterpret_cast<const float4*>(&hs[i + 4]);
        __hip_bfloat16 o[8] __attribute__((aligned(16)));
        o[0] = __float2bfloat16(a.x); o[1] = __float2bfloat16(a.y);
        o[2] = __float2bfloat16(a.z); o[3] = __float2bfloat16(a.w);
        o[4] = __float2bfloat16(c.x); o[5] = __float2bfloat16(c.y);
        o[6] = __float2bfloat16(c.z); o[7] = __float2bfloat16(c.w);
        *reinterpret_cast<bx8*>(&hsb[i]) = *reinterpret_cast<bx8*>(o);
        return;
    }
    b -= 2048;
    const float* src; __hip_bfloat16* dst; int Nd, bx, by;
    if (b < 4096)      { src = Wq; dst = WqkvT;                        Nd = 2048; bx = b & 63; by = b >> 6; }
    else if (b < 5120) { b -= 4096; src = Wk; dst = WqkvT + (size_t)2048 * 2048; Nd = 512; bx = b & 15; by = b >> 4; }
    else if (b < 6144) { b -= 5120; src = Wv; dst = WqkvT + (size_t)2560 * 2048; Nd = 512; bx = b & 15; by = b >> 4; }
    else               { b -= 6144; src = Wo; dst = WoT;               Nd = 2048; bx = b & 63; by = b >> 6; }
    int n0 = bx * 32, k0 = by * 32, tx = t & 31, ty = t >> 5;  // 32 x 8
#pragma unroll
    for (int i = 0; i < 4; i++)
        tile[ty + 8 * i][tx] = src[(size_t)(k0 + ty + 8 * i) * Nd + n0 + tx];
    __syncthreads();
#pragma unroll
    for (int i = 0; i < 4; i++)
        dst[(size_t)(n0 + ty + 8 * i) * 2048 + k0 + tx] = __float2bfloat16(tile[tx][ty + 8 * i]);
}

// ---------------- rope (Q+K) + vtrans, ONE dispatch ----------------
__global__ __launch_bounds__(256) void ropev_kernel(__hip_bfloat16* __restrict__ QKV,
                                                    __hip_bfloat16* __restrict__ Vt,
                                                    const float* __restrict__ cosT,
                                                    const float* __restrict__ sinT) {
    __shared__ __hip_bfloat16 tile[32][33];
    int b = blockIdx.x, t = threadIdx.x;
    if (b < 10240) {
        int idx = b * 256 + t;           // s*(40*32) + head*32 + f
        int f = idx & 31;
        int head = (idx >> 5) % (NH + NKV);
        int s = idx / ((NH + NKV) * 32);
        float c  = cosT[(s << 5) + f];
        float sn = sinT[(s << 5) + f];
        __hip_bfloat16* p = (head < NH) ? (QKV + (size_t)s * QKVN + head * HD)
                                        : (QKV + (size_t)s * QKVN + 2048 + (head - NH) * HD);
        float x1 = __bfloat162float(p[f]), x2 = __bfloat162float(p[f + 32]);
        p[f]      = __float2bfloat16(x1 * c - x2 * sn);
        p[f + 32] = __float2bfloat16(x2 * c + x1 * sn);
        return;
    }
    b -= 10240;
    int s0 = (b & 63) * 32, d0 = (b >> 6) * 32;
    int tx = t & 31, ty = t >> 5;  // 32 x 8
#pragma unroll
    for (int i = 0; i < 4; i++)
        tile[ty + 8 * i][tx] = QKV[(size_t)(s0 + ty + 8 * i) * QKVN + 2560 + d0 + tx];
    __syncthreads();
#pragma unroll
    for (int i = 0; i < 4; i++)
        Vt[(size_t)(d0 + ty + 8 * i) * S_LEN + s0 + tx] = tile[tx][ty + 8 * i];
}

// ---------------- pipelined bf16 MFMA GEMM, 64x128 tile, XCD N-striped (frozen R14) ----------------
template <int OUTBF16>
__global__ __launch_bounds__(256) void gemm_pipe_kernel(const __hip_bfloat16* __restrict__ A,
                                                        const __hip_bfloat16* __restrict__ Bt,
                                                        void* __restrict__ Cp,
                                                        int M, int N, int K, int stripe) {
    __shared__ __hip_bfloat16 As[3][2048];   // 3 x [64 rows][32 k]
    __shared__ __hip_bfloat16 Bs[3][4096];   // 3 x [128 rows][32 k]

    const int bid = blockIdx.x;
    const int x = bid & 7, j = bid >> 3;
    const int bn = (x * stripe + j % stripe) * 128;
    const int bm = (j / stripe) * 64;

    const int t = threadIdx.x, w = t >> 6, l = t & 63;
    const int wr = (w >> 1) * 32, wc = (w & 1) * 64;
    const int lr = l & 15;
    const int rdslot = (((l >> 4) ^ ((lr >> 1) & 3))) * 8;
    const int srow = w * 16 + (l >> 2);
    const int scol = (((l & 3) ^ ((l >> 3) & 3))) * 8;
    const int ldsoff = w * 512;

    const __hip_bfloat16* ga0 = A + (size_t)(bm + srow) * K + scol;
    const __hip_bfloat16* gb0 = Bt + (size_t)(bn + srow) * K + scol;
    const size_t half = (size_t)64 * K;

    fx4 acc[2][4];
#pragma unroll
    for (int m = 0; m < 2; m++)
#pragma unroll
        for (int n = 0; n < 4; n++) acc[m][n] = (fx4){0.f, 0.f, 0.f, 0.f};

    const int T = K >> 5;

#define STAGE(kt, b)                                              \
    do {                                                          \
        const __hip_bfloat16* ga = ga0 + (kt) * 32;               \
        const __hip_bfloat16* gb = gb0 + (kt) * 32;               \
        GL_LDS16(ga,        &As[(b)][ldsoff]);                    \
        GL_LDS16(gb,        &Bs[(b)][ldsoff]);                    \
        GL_LDS16(gb + half, &Bs[(b)][2048 + ldsoff]);             \
    } while (0)

    STAGE(0, 0);
    STAGE(1, 1);

    for (int i = 0; i < T; i++) {
        const int r = i % 3;
        if (i + 1 < T) asm volatile("s_waitcnt vmcnt(3)" ::: "memory");
        else           asm volatile("s_waitcnt vmcnt(0)" ::: "memory");
        __builtin_amdgcn_s_barrier();
        asm volatile("" ::: "memory");
        if (i + 2 < T) STAGE(i + 2, (i + 2) % 3);

        bx8 af[2], bf[4];
#pragma unroll
        for (int m = 0; m < 2; m++)
            af[m] = *reinterpret_cast<const bx8*>(&As[r][(wr + m * 16 + lr) * 32 + rdslot]);
#pragma unroll
        for (int n = 0; n < 4; n++)
            bf[n] = *reinterpret_cast<const bx8*>(&Bs[r][(wc + n * 16 + lr) * 32 + rdslot]);
#pragma unroll
        for (int m = 0; m < 2; m++)
#pragma unroll
            for (int n = 0; n < 4; n++)
                acc[m][n] = __builtin_amdgcn_mfma_f32_16x16x32_bf16(af[m], bf[n], acc[m][n], 0, 0, 0);
    }
#undef STAGE

    const int lq = (l >> 4) * 4;
#pragma unroll
    for (int m = 0; m < 2; m++)
#pragma unroll
        for (int n = 0; n < 4; n++)
#pragma unroll
            for (int r2 = 0; r2 < 4; r2++) {
                int row = bm + wr + m * 16 + lq + r2;
                int col = bn + wc + n * 16 + lr;
                float v = acc[m][n][r2];
                if (OUTBF16)
                    ((__hip_bfloat16*)Cp)[(size_t)row * N + col] = __float2bfloat16(v);
                else
                    ((float*)Cp)[(size_t)row * N + col] = v;
            }
}

// ---------------- MFMA sliding-window flash attention, swapped-operand softmax ----------------
// R17: R15 base (QBLK=128, gl_lds staging, single barrier/tile) + two exact
// wave-uniform wins: (1) skip tiles fully below the wave's window,
// (2) defer-rescale when no lane's max grew (fs==1 exactly).
__global__ __launch_bounds__(512, 4) void attn_kernel(const __hip_bfloat16* __restrict__ Q,
                                                      const __hip_bfloat16* __restrict__ Kg,
                                                      const __hip_bfloat16* __restrict__ Vtg,
                                                      __hip_bfloat16* __restrict__ Ab) {
    __shared__ __hip_bfloat16 Ks[2][4096];
    __shared__ __hip_bfloat16 Vs[2][4096];
    __shared__ __hip_bfloat16 Ps[QBLK * 64];

    const int bid = blockIdx.x;
    const int swz = (bid & 7) * 64 + (bid >> 3);
    const int h = swz >> 4, qi = swz & 15;
    const int qb = qi * QBLK;
    const int kvh = h >> 2;

    const int t = threadIdx.x, w = t >> 6, l = t & 63;
    const int lr = l & 15, g = l >> 4, lk = g * 8;
    const int qbw = qb + 16 * w;      // this wave's 16 q-rows
    const int prow = 16 * w + lr;     // this lane's q-row in Ps
    const int psz = (prow & 7) << 4;

    char* PsB = (char*)Ps;

    // hoisted Q fragments (B-operand; lane holds q-row lr)
    bx8 qa[2];
#pragma unroll
    for (int ks = 0; ks < 2; ks++)
        qa[ks] = *reinterpret_cast<const bx8*>(
            &Q[(size_t)(qbw + lr) * QKVN + h * HD + ks * 32 + lk]);

    fx4 ot[4];
#pragma unroll
    for (int n = 0; n < 4; n++) ot[n] = (fx4){0.f, 0.f, 0.f, 0.f};
    float mrow = -1e30f, srow = 0.f;

    const int k0_first = (qb >= 1024) ? (qb - 1024) : 0;
    const int k0_last  = qb + 64;
    const int wmax = qbw + 15;
    const int wlow = qbw - (WINDOW - 1);      // lowest valid key for this wave
    const int rowq = qbw + lr;                // this lane's q-row (global)

    // staging: thread t covers row sr=t>>3, 16B chunk c8=t&7.
    // LDS dst is LINEAR; global src col pre-swizzled (content == old XOR layout).
    const int sr = t >> 3, c8 = t & 7;
    const int scolsw = 8 * (c8 ^ (sr & 7));
    const int kcol = kvh * HD + scolsw;
    const int vrow = kvh * HD + sr;
    __hip_bfloat16* ldsK = &Ks[0][0] + (t >> 6) * 512;
    __hip_bfloat16* ldsV = &Vs[0][0] + (t >> 6) * 512;

#define ASTAGE(k0v, p)                                                           \
    do {                                                                         \
        GL_LDS16(&Kg[(size_t)((k0v) + sr) * QKVN + kcol], ldsK + (p) * 4096);    \
        GL_LDS16(&Vtg[(size_t)vrow * S_LEN + (k0v) + scolsw], ldsV + (p) * 4096);\
    } while (0)

    ASTAGE(k0_first, 0);

    int ti = 0;
    for (int k0 = k0_first; k0 <= k0_last; k0 += 64, ++ti) {
        const int p = ti & 1;
        asm volatile("s_waitcnt vmcnt(0)" ::: "memory");
        __builtin_amdgcn_s_barrier();
        asm volatile("" ::: "memory");
        if (k0 + 64 <= k0_last) ASTAGE(k0 + 64, p ^ 1);

        // skip tiles above this wave's rows OR fully below its window (exact)
        if (k0 <= wmax && k0 + 63 >= wlow) {
            char* KsB = (char*)&Ks[p][0];
            char* VsB = (char*)&Vs[p][0];
            // K fragments (A-operand: rows = keys)
            bx8 kb[4][2];
#pragma unroll
            for (int n = 0; n < 4; n++)
#pragma unroll
                for (int ks = 0; ks < 2; ks++) {
                    int row = 16 * n + lr;
                    kb[n][ks] = *reinterpret_cast<const bx8*>(
                        KsB + row * 128 + (((ks * 64) + 16 * g) ^ ((row & 7) << 4)));
                }
            // S^T = K · Q^T : rows=keys (16n+4g+r), cols=q (lr)
            fx4 sc[4];
#pragma unroll
            for (int n = 0; n < 4; n++) {
                sc[n] = __builtin_amdgcn_mfma_f32_16x16x32_bf16(kb[n][0], qa[0],
                                                                (fx4){0.f, 0.f, 0.f, 0.f}, 0, 0, 0);
                sc[n] = __builtin_amdgcn_mfma_f32_16x16x32_bf16(kb[n][1], qa[1], sc[n], 0, 0, 0);
            }
            // scale + sliding-window mask (interior tiles skip the mask)
            const bool interior = (k0 + 63 <= qbw) && (k0 >= qbw - 1008);
            if (interior) {
#pragma unroll
                for (int n = 0; n < 4; n++)
#pragma unroll
                    for (int r = 0; r < 4; r++) sc[n][r] *= 0.125f;
            } else {
#pragma unroll
                for (int n = 0; n < 4; n++)
#pragma unroll
                    for (int r = 0; r < 4; r++) {
                        int key = k0 + 16 * n + 4 * g + r;
                        bool valid = (key <= rowq) && (key >= rowq - (WINDOW - 1));
                        sc[n][r] = valid ? sc[n][r] * 0.125f : -1e30f;
                    }
            }
            // in-register row max
            float tmax = fmaxf(fmaxf(sc[0][0], sc[0][1]), fmaxf(sc[0][2], sc[0][3]));
#pragma unroll
            for (int n = 1; n < 4; n++)
                tmax = fmaxf(tmax, fmaxf(fmaxf(sc[n][0], sc[n][1]), fmaxf(sc[n][2], sc[n][3])));
            tmax = fmaxf(tmax, __shfl_xor(tmax, 16));
            tmax = fmaxf(tmax, __shfl_xor(tmax, 32));
            // exact defer-rescale: if no lane's max grew, fs==1 for the whole wave
            const bool grew = __any(tmax > mrow);
            float mn = mrow, fs = 1.f;
            if (grew) {
                mn = fmaxf(mrow, tmax);
                fs = __expf(mrow - mn);
                mrow = mn;
            }
            // exp + P^T write (packed b64, lane's own row) + sum
            float ps = 0.f;
#pragma unroll
            for (int n = 0; n < 4; n++) {
#pragma unroll
                for (int r = 0; r < 4; r++) {
                    float p2 = __expf(sc[n][r] - mn);
                    sc[n][r] = p2;
                    ps += p2;
                }
                __hip_bfloat16 pk[4] __attribute__((aligned(8)));
                pk[0] = __float2bfloat16(sc[n][0]); pk[1] = __float2bfloat16(sc[n][1]);
                pk[2] = __float2bfloat16(sc[n][2]); pk[3] = __float2bfloat16(sc[n][3]);
                *reinterpret_cast<unsigned long long*>(PsB + prow * 128 + ((32 * n + 8 * g) ^ psz)) =
                    *reinterpret_cast<unsigned long long*>(pk);
            }
            ps += __shfl_xor(ps, 16);
            ps += __shfl_xor(ps, 32);
            if (grew) {
                srow = srow * fs + ps;
#pragma unroll
                for (int n = 0; n < 4; n++)
#pragma unroll
                    for (int r = 0; r < 4; r++) ot[n][r] *= fs;
            } else {
                srow += ps;
            }
            // V fragments (A-operand: rows = d) + P fragments (B-operand: rows = q)
            bx8 vb[4][2];
#pragma unroll
            for (int n = 0; n < 4; n++)
#pragma unroll
                for (int ks = 0; ks < 2; ks++) {
                    int row = 16 * n + lr;
                    vb[n][ks] = *reinterpret_cast<const bx8*>(
                        VsB + row * 128 + (((ks * 64) + 16 * g) ^ ((row & 7) << 4)));
                }
            bx8 pb[2];
#pragma unroll
            for (int ks = 0; ks < 2; ks++)
                pb[ks] = *reinterpret_cast<const bx8*>(
                    PsB + prow * 128 + (((ks * 64) + 16 * g) ^ psz));
            // O^T += V^T · P : rows=d (16n+4g+r), cols=q (lr)
#pragma unroll
            for (int n = 0; n < 4; n++) {
                ot[n] = __builtin_amdgcn_mfma_f32_16x16x32_bf16(vb[n][0], pb[0], ot[n], 0, 0, 0);
                ot[n] = __builtin_amdgcn_mfma_f32_16x16x32_bf16(vb[n][1], pb[1], ot[n], 0, 0, 0);
            }
        }
    }
#undef ASTAGE

    // ---- epilogue: normalize, O^T frags -> Ps as [q][d] (b64+XOR), then
    // cooperative coalesced row-major store to Ab (128 rows x 8 chunks) ----
    const float inv = 1.f / srow;
#pragma unroll
    for (int n = 0; n < 4; n++) {
        __hip_bfloat16 pk[4] __attribute__((aligned(8)));
#pragma unroll
        for (int r = 0; r < 4; r++) pk[r] = __float2bfloat16(ot[n][r] * inv);
        *reinterpret_cast<unsigned long long*>(PsB + prow * 128 + ((32 * n + 8 * g) ^ psz)) =
            *reinterpret_cast<unsigned long long*>(pk);
    }
    __syncthreads();
#pragma unroll
    for (int j = 0; j < 2; j++) {
        const int row = (t >> 3) + 64 * j, c = t & 7;   // 128 rows x 8 us8-chunks
        us8 v = *reinterpret_cast<const us8*>(PsB + row * 128 + ((c * 16) ^ ((row & 7) << 4)));
        *reinterpret_cast<us8*>(&Ab[(size_t)(qb + row) * HID + h * HD + c * 8]) = v;
    }
}

extern "C" void kernel_launch(void* const* d_in, const int* in_sizes, int n_in,
                              void* d_out, int out_size, void* d_ws, size_t ws_size,
                              hipStream_t stream) {
    const float* hs = (const float*)d_in[0];
    const float* Wq = (const float*)d_in[1];
    const float* Wk = (const float*)d_in[2];
    const float* Wv = (const float*)d_in[3];
    const float* Wo = (const float*)d_in[4];

    float* ws   = (float*)d_ws;
    float* cosT = ws;                  // 65536 f32
    float* sinT = cosT + 65536;        // 65536 f32
    __hip_bfloat16* hsb    = (__hip_bfloat16*)(sinT + 65536);   // [2048][2048]
    __hip_bfloat16* WqkvT  = hsb + 4194304;                     // [3072][2048]: Wq|Wk|Wv rows
    __hip_bfloat16* WoT    = WqkvT + 6291456;                   // [2048][2048]
    __hip_bfloat16* QKVb   = WoT + 4194304;                     // [2048][3072]
    __hip_bfloat16* Vt     = QKVb + 6291456;                    // [512][2048]
    __hip_bfloat16* Ab     = hsb;                               // alias: hsb dead after QKV gemm

    // prep: tables + hs->bf16 + weight transposes (one dispatch)
    prep_kernel<<<12544, 256, 0, stream>>>(hs, Wq, Wk, Wv, Wo, cosT, sinT, hsb, WqkvT, WoT);

    // fused QKV projection (64x128 tiles, 768 blocks, XCD stripe=3)
    gemm_pipe_kernel<1><<<768, 256, 0, stream>>>(hsb, WqkvT, QKVb, 2048, QKVN, 2048, 3);

    // RoPE (Q+K) + V transpose (one dispatch)
    ropev_kernel<<<11264, 256, 0, stream>>>(QKVb, Vt, cosT, sinT);

    // attention: 128-row blocks, 8 waves x 16 rows, writes row-major Ab directly
    attn_kernel<<<512, 512, 0, stream>>>(QKVb, QKVb + 2048, Vt, Ab);

    // output projection (64x128 tiles, 512 blocks, XCD stripe=2)
    gemm_pipe_kernel<0><<<512, 256, 0, stream>>>(Ab, WoT, d_out, 2048, 2048, 2048, 2);
}

// Round 18
// 144.237 us; speedup vs baseline: 1.0667x; 1.0015x over previous
//
#include <hip/hip_runtime.h>
#include <hip/hip_bf16.h>
#include <math.h>

#define S_LEN 2048
#define HID 2048
#define NH 32
#define NKV 8
#define HD 64
#define WINDOW 1024
#define QBLK 128
#define QKVN 3072   // fused Q(2048) | K(512) | V(512) columns

typedef __attribute__((ext_vector_type(8))) short bx8;          // 8 bf16 (4 VGPRs) — MFMA A/B frag
typedef __attribute__((ext_vector_type(4))) float fx4;          // MFMA C/D frag
typedef __attribute__((ext_vector_type(8))) unsigned short us8; // 8 bf16 raw

#define GL_LDS16(gp, lp) \
    __builtin_amdgcn_global_load_lds((__attribute__((address_space(1))) const void*)(gp), \
                                     (__attribute__((address_space(3))) void*)(lp), 16, 0, 0)

// ---------------- prep: rope tables + hs conv + 4 weight transposes, ONE dispatch ----------------
__global__ __launch_bounds__(256) void prep_kernel(const float* __restrict__ hs,
                                                   const float* __restrict__ Wq,
                                                   const float* __restrict__ Wk,
                                                   const float* __restrict__ Wv,
                                                   const float* __restrict__ Wo,
                                                   float* __restrict__ cosT, float* __restrict__ sinT,
                                                   __hip_bfloat16* __restrict__ hsb,
                                                   __hip_bfloat16* __restrict__ WqkvT,
                                                   __hip_bfloat16* __restrict__ WoT) {
    __shared__ float tile[32][33];
    int b = blockIdx.x, t = threadIdx.x;
    if (b < 256) {
        int idx = b * 256 + t;           // s*32 + f
        int s = idx >> 5, f = idx & 31;
        double inv = exp(-2.0 * (double)f / 64.0 * log(500000.0));
        double ang = (double)s * inv;
        cosT[idx] = (float)cos(ang);
        sinT[idx] = (float)sin(ang);
        return;
    }
    b -= 256;
    if (b < 2048) {
        int i = (b * 256 + t) * 8;
        float4 a = *reinterpret_cast<const float4*>(&hs[i]);
        float4 c = *reinterpret_cast<const float4*>(&hs[i + 4]);
        __hip_bfloat16 o[8] __attribute__((aligned(16)));
        o[0] = __float2bfloat16(a.x); o[1] = __float2bfloat16(a.y);
        o[2] = __float2bfloat16(a.z); o[3] = __float2bfloat16(a.w);
        o[4] = __float2bfloat16(c.x); o[5] = __float2bfloat16(c.y);
        o[6] = __float2bfloat16(c.z); o[7] = __float2bfloat16(c.w);
        *reinterpret_cast<bx8*>(&hsb[i]) = *reinterpret_cast<bx8*>(o);
        return;
    }
    b -= 2048;
    const float* src; __hip_bfloat16* dst; int Nd, bx, by;
    if (b < 4096)      { src = Wq; dst = WqkvT;                        Nd = 2048; bx = b & 63; by = b >> 6; }
    else if (b < 5120) { b -= 4096; src = Wk; dst = WqkvT + (size_t)2048 * 2048; Nd = 512; bx = b & 15; by = b >> 4; }
    else if (b < 6144) { b -= 5120; src = Wv; dst = WqkvT + (size_t)2560 * 2048; Nd = 512; bx = b & 15; by = b >> 4; }
    else               { b -= 6144; src = Wo; dst = WoT;               Nd = 2048; bx = b & 63; by = b >> 6; }
    int n0 = bx * 32, k0 = by * 32, tx = t & 31, ty = t >> 5;  // 32 x 8
#pragma unroll
    for (int i = 0; i < 4; i++)
        tile[ty + 8 * i][tx] = src[(size_t)(k0 + ty + 8 * i) * Nd + n0 + tx];
    __syncthreads();
#pragma unroll
    for (int i = 0; i < 4; i++)
        dst[(size_t)(n0 + ty + 8 * i) * 2048 + k0 + tx] = __float2bfloat16(tile[tx][ty + 8 * i]);
}

// ---------------- rope (Q+K) + vtrans, ONE dispatch ----------------
__global__ __launch_bounds__(256) void ropev_kernel(__hip_bfloat16* __restrict__ QKV,
                                                    __hip_bfloat16* __restrict__ Vt,
                                                    const float* __restrict__ cosT,
                                                    const float* __restrict__ sinT) {
    __shared__ __hip_bfloat16 tile[32][33];
    int b = blockIdx.x, t = threadIdx.x;
    if (b < 10240) {
        int idx = b * 256 + t;           // s*(40*32) + head*32 + f
        int f = idx & 31;
        int head = (idx >> 5) % (NH + NKV);
        int s = idx / ((NH + NKV) * 32);
        float c  = cosT[(s << 5) + f];
        float sn = sinT[(s << 5) + f];
        __hip_bfloat16* p = (head < NH) ? (QKV + (size_t)s * QKVN + head * HD)
                                        : (QKV + (size_t)s * QKVN + 2048 + (head - NH) * HD);
        float x1 = __bfloat162float(p[f]), x2 = __bfloat162float(p[f + 32]);
        p[f]      = __float2bfloat16(x1 * c - x2 * sn);
        p[f + 32] = __float2bfloat16(x2 * c + x1 * sn);
        return;
    }
    b -= 10240;
    int s0 = (b & 63) * 32, d0 = (b >> 6) * 32;
    int tx = t & 31, ty = t >> 5;  // 32 x 8
#pragma unroll
    for (int i = 0; i < 4; i++)
        tile[ty + 8 * i][tx] = QKV[(size_t)(s0 + ty + 8 * i) * QKVN + 2560 + d0 + tx];
    __syncthreads();
#pragma unroll
    for (int i = 0; i < 4; i++)
        Vt[(size_t)(d0 + ty + 8 * i) * S_LEN + s0 + tx] = tile[tx][ty + 8 * i];
}

// ---------------- pipelined bf16 MFMA GEMM, 64x128 tile, XCD N-striped ----------------
// R18: prefetch depth 3 (4 LDS buffers, vmcnt(6) steady-state) — two tiles stay
// in flight across the barrier, doubling the latency budget vs depth 2.
template <int OUTBF16>
__global__ __launch_bounds__(256) void gemm_pipe_kernel(const __hip_bfloat16* __restrict__ A,
                                                        const __hip_bfloat16* __restrict__ Bt,
                                                        void* __restrict__ Cp,
                                                        int M, int N, int K, int stripe) {
    __shared__ __hip_bfloat16 As[4][2048];   // 4 x [64 rows][32 k]
    __shared__ __hip_bfloat16 Bs[4][4096];   // 4 x [128 rows][32 k]

    const int bid = blockIdx.x;
    const int x = bid & 7, j = bid >> 3;
    const int bn = (x * stripe + j % stripe) * 128;
    const int bm = (j / stripe) * 64;

    const int t = threadIdx.x, w = t >> 6, l = t & 63;
    const int wr = (w >> 1) * 32, wc = (w & 1) * 64;
    const int lr = l & 15;
    const int rdslot = (((l >> 4) ^ ((lr >> 1) & 3))) * 8;
    const int srow = w * 16 + (l >> 2);
    const int scol = (((l & 3) ^ ((l >> 3) & 3))) * 8;
    const int ldsoff = w * 512;

    const __hip_bfloat16* ga0 = A + (size_t)(bm + srow) * K + scol;
    const __hip_bfloat16* gb0 = Bt + (size_t)(bn + srow) * K + scol;
    const size_t half = (size_t)64 * K;

    fx4 acc[2][4];
#pragma unroll
    for (int m = 0; m < 2; m++)
#pragma unroll
        for (int n = 0; n < 4; n++) acc[m][n] = (fx4){0.f, 0.f, 0.f, 0.f};

    const int T = K >> 5;

#define STAGE(kt, b)                                              \
    do {                                                          \
        const __hip_bfloat16* ga = ga0 + (kt) * 32;               \
        const __hip_bfloat16* gb = gb0 + (kt) * 32;               \
        GL_LDS16(ga,        &As[(b)][ldsoff]);                    \
        GL_LDS16(gb,        &Bs[(b)][ldsoff]);                    \
        GL_LDS16(gb + half, &Bs[(b)][2048 + ldsoff]);             \
    } while (0)

    STAGE(0, 0);
    STAGE(1, 1);
    STAGE(2, 2);

    for (int i = 0; i < T; i++) {
        const int r = i & 3;
        if (i + 2 < T)      asm volatile("s_waitcnt vmcnt(6)" ::: "memory");
        else if (i + 1 < T) asm volatile("s_waitcnt vmcnt(3)" ::: "memory");
        else                asm volatile("s_waitcnt vmcnt(0)" ::: "memory");
        __builtin_amdgcn_s_barrier();
        asm volatile("" ::: "memory");
        if (i + 3 < T) STAGE(i + 3, (i + 3) & 3);

        bx8 af[2], bf[4];
#pragma unroll
        for (int m = 0; m < 2; m++)
            af[m] = *reinterpret_cast<const bx8*>(&As[r][(wr + m * 16 + lr) * 32 + rdslot]);
#pragma unroll
        for (int n = 0; n < 4; n++)
            bf[n] = *reinterpret_cast<const bx8*>(&Bs[r][(wc + n * 16 + lr) * 32 + rdslot]);
#pragma unroll
        for (int m = 0; m < 2; m++)
#pragma unroll
            for (int n = 0; n < 4; n++)
                acc[m][n] = __builtin_amdgcn_mfma_f32_16x16x32_bf16(af[m], bf[n], acc[m][n], 0, 0, 0);
    }
#undef STAGE

    const int lq = (l >> 4) * 4;
#pragma unroll
    for (int m = 0; m < 2; m++)
#pragma unroll
        for (int n = 0; n < 4; n++)
#pragma unroll
            for (int r2 = 0; r2 < 4; r2++) {
                int row = bm + wr + m * 16 + lq + r2;
                int col = bn + wc + n * 16 + lr;
                float v = acc[m][n][r2];
                if (OUTBF16)
                    ((__hip_bfloat16*)Cp)[(size_t)row * N + col] = __float2bfloat16(v);
                else
                    ((float*)Cp)[(size_t)row * N + col] = v;
            }
}

// ---------------- MFMA sliding-window flash attention, swapped-operand softmax (frozen R17) ----------------
__global__ __launch_bounds__(512, 4) void attn_kernel(const __hip_bfloat16* __restrict__ Q,
                                                      const __hip_bfloat16* __restrict__ Kg,
                                                      const __hip_bfloat16* __restrict__ Vtg,
                                                      __hip_bfloat16* __restrict__ Ab) {
    __shared__ __hip_bfloat16 Ks[2][4096];
    __shared__ __hip_bfloat16 Vs[2][4096];
    __shared__ __hip_bfloat16 Ps[QBLK * 64];

    const int bid = blockIdx.x;
    const int swz = (bid & 7) * 64 + (bid >> 3);
    const int h = swz >> 4, qi = swz & 15;
    const int qb = qi * QBLK;
    const int kvh = h >> 2;

    const int t = threadIdx.x, w = t >> 6, l = t & 63;
    const int lr = l & 15, g = l >> 4, lk = g * 8;
    const int qbw = qb + 16 * w;      // this wave's 16 q-rows
    const int prow = 16 * w + lr;     // this lane's q-row in Ps
    const int psz = (prow & 7) << 4;

    char* PsB = (char*)Ps;

    // hoisted Q fragments (B-operand; lane holds q-row lr)
    bx8 qa[2];
#pragma unroll
    for (int ks = 0; ks < 2; ks++)
        qa[ks] = *reinterpret_cast<const bx8*>(
            &Q[(size_t)(qbw + lr) * QKVN + h * HD + ks * 32 + lk]);

    fx4 ot[4];
#pragma unroll
    for (int n = 0; n < 4; n++) ot[n] = (fx4){0.f, 0.f, 0.f, 0.f};
    float mrow = -1e30f, srow = 0.f;

    const int k0_first = (qb >= 1024) ? (qb - 1024) : 0;
    const int k0_last  = qb + 64;
    const int wmax = qbw + 15;
    const int wlow = qbw - (WINDOW - 1);
    const int rowq = qbw + lr;

    const int sr = t >> 3, c8 = t & 7;
    const int scolsw = 8 * (c8 ^ (sr & 7));
    const int kcol = kvh * HD + scolsw;
    const int vrow = kvh * HD + sr;
    __hip_bfloat16* ldsK = &Ks[0][0] + (t >> 6) * 512;
    __hip_bfloat16* ldsV = &Vs[0][0] + (t >> 6) * 512;

#define ASTAGE(k0v, p)                                                           \
    do {                                                                         \
        GL_LDS16(&Kg[(size_t)((k0v) + sr) * QKVN + kcol], ldsK + (p) * 4096);    \
        GL_LDS16(&Vtg[(size_t)vrow * S_LEN + (k0v) + scolsw], ldsV + (p) * 4096);\
    } while (0)

    ASTAGE(k0_first, 0);

    int ti = 0;
    for (int k0 = k0_first; k0 <= k0_last; k0 += 64, ++ti) {
        const int p = ti & 1;
        asm volatile("s_waitcnt vmcnt(0)" ::: "memory");
        __builtin_amdgcn_s_barrier();
        asm volatile("" ::: "memory");
        if (k0 + 64 <= k0_last) ASTAGE(k0 + 64, p ^ 1);

        if (k0 <= wmax && k0 + 63 >= wlow) {
            char* KsB = (char*)&Ks[p][0];
            char* VsB = (char*)&Vs[p][0];
            bx8 kb[4][2];
#pragma unroll
            for (int n = 0; n < 4; n++)
#pragma unroll
                for (int ks = 0; ks < 2; ks++) {
                    int row = 16 * n + lr;
                    kb[n][ks] = *reinterpret_cast<const bx8*>(
                        KsB + row * 128 + (((ks * 64) + 16 * g) ^ ((row & 7) << 4)));
                }
            fx4 sc[4];
#pragma unroll
            for (int n = 0; n < 4; n++) {
                sc[n] = __builtin_amdgcn_mfma_f32_16x16x32_bf16(kb[n][0], qa[0],
                                                                (fx4){0.f, 0.f, 0.f, 0.f}, 0, 0, 0);
                sc[n] = __builtin_amdgcn_mfma_f32_16x16x32_bf16(kb[n][1], qa[1], sc[n], 0, 0, 0);
            }
            const bool interior = (k0 + 63 <= qbw) && (k0 >= qbw - 1008);
            if (interior) {
#pragma unroll
                for (int n = 0; n < 4; n++)
#pragma unroll
                    for (int r = 0; r < 4; r++) sc[n][r] *= 0.125f;
            } else {
#pragma unroll
                for (int n = 0; n < 4; n++)
#pragma unroll
                    for (int r = 0; r < 4; r++) {
                        int key = k0 + 16 * n + 4 * g + r;
                        bool valid = (key <= rowq) && (key >= rowq - (WINDOW - 1));
                        sc[n][r] = valid ? sc[n][r] * 0.125f : -1e30f;
                    }
            }
            float tmax = fmaxf(fmaxf(sc[0][0], sc[0][1]), fmaxf(sc[0][2], sc[0][3]));
#pragma unroll
            for (int n = 1; n < 4; n++)
                tmax = fmaxf(tmax, fmaxf(fmaxf(sc[n][0], sc[n][1]), fmaxf(sc[n][2], sc[n][3])));
            tmax = fmaxf(tmax, __shfl_xor(tmax, 16));
            tmax = fmaxf(tmax, __shfl_xor(tmax, 32));
            const bool grew = __any(tmax > mrow);
            float mn = mrow, fs = 1.f;
            if (grew) {
                mn = fmaxf(mrow, tmax);
                fs = __expf(mrow - mn);
                mrow = mn;
            }
            float ps = 0.f;
#pragma unroll
            for (int n = 0; n < 4; n++) {
#pragma unroll
                for (int r = 0; r < 4; r++) {
                    float p2 = __expf(sc[n][r] - mn);
                    sc[n][r] = p2;
                    ps += p2;
                }
                __hip_bfloat16 pk[4] __attribute__((aligned(8)));
                pk[0] = __float2bfloat16(sc[n][0]); pk[1] = __float2bfloat16(sc[n][1]);
                pk[2] = __float2bfloat16(sc[n][2]); pk[3] = __float2bfloat16(sc[n][3]);
                *reinterpret_cast<unsigned long long*>(PsB + prow * 128 + ((32 * n + 8 * g) ^ psz)) =
                    *reinterpret_cast<unsigned long long*>(pk);
            }
            ps += __shfl_xor(ps, 16);
            ps += __shfl_xor(ps, 32);
            if (grew) {
                srow = srow * fs + ps;
#pragma unroll
                for (int n = 0; n < 4; n++)
#pragma unroll
                    for (int r = 0; r < 4; r++) ot[n][r] *= fs;
            } else {
                srow += ps;
            }
            bx8 vb[4][2];
#pragma unroll
            for (int n = 0; n < 4; n++)
#pragma unroll
                for (int ks = 0; ks < 2; ks++) {
                    int row = 16 * n + lr;
                    vb[n][ks] = *reinterpret_cast<const bx8*>(
                        VsB + row * 128 + (((ks * 64) + 16 * g) ^ ((row & 7) << 4)));
                }
            bx8 pb[2];
#pragma unroll
            for (int ks = 0; ks < 2; ks++)
                pb[ks] = *reinterpret_cast<const bx8*>(
                    PsB + prow * 128 + (((ks * 64) + 16 * g) ^ psz));
#pragma unroll
            for (int n = 0; n < 4; n++) {
                ot[n] = __builtin_amdgcn_mfma_f32_16x16x32_bf16(vb[n][0], pb[0], ot[n], 0, 0, 0);
                ot[n] = __builtin_amdgcn_mfma_f32_16x16x32_bf16(vb[n][1], pb[1], ot[n], 0, 0, 0);
            }
        }
    }
#undef ASTAGE

    const float inv = 1.f / srow;
#pragma unroll
    for (int n = 0; n < 4; n++) {
        __hip_bfloat16 pk[4] __attribute__((aligned(8)));
#pragma unroll
        for (int r = 0; r < 4; r++) pk[r] = __float2bfloat16(ot[n][r] * inv);
        *reinterpret_cast<unsigned long long*>(PsB + prow * 128 + ((32 * n + 8 * g) ^ psz)) =
            *reinterpret_cast<unsigned long long*>(pk);
    }
    __syncthreads();
#pragma unroll
    for (int j = 0; j < 2; j++) {
        const int row = (t >> 3) + 64 * j, c = t & 7;   // 128 rows x 8 us8-chunks
        us8 v = *reinterpret_cast<const us8*>(PsB + row * 128 + ((c * 16) ^ ((row & 7) << 4)));
        *reinterpret_cast<us8*>(&Ab[(size_t)(qb + row) * HID + h * HD + c * 8]) = v;
    }
}

extern "C" void kernel_launch(void* const* d_in, const int* in_sizes, int n_in,
                              void* d_out, int out_size, void* d_ws, size_t ws_size,
                              hipStream_t stream) {
    const float* hs = (const float*)d_in[0];
    const float* Wq = (const float*)d_in[1];
    const float* Wk = (const float*)d_in[2];
    const float* Wv = (const float*)d_in[3];
    const float* Wo = (const float*)d_in[4];

    float* ws   = (float*)d_ws;
    float* cosT = ws;                  // 65536 f32
    float* sinT = cosT + 65536;        // 65536 f32
    __hip_bfloat16* hsb    = (__hip_bfloat16*)(sinT + 65536);   // [2048][2048]
    __hip_bfloat16* WqkvT  = hsb + 4194304;                     // [3072][2048]: Wq|Wk|Wv rows
    __hip_bfloat16* WoT    = WqkvT + 6291456;                   // [2048][2048]
    __hip_bfloat16* QKVb   = WoT + 4194304;                     // [2048][3072]
    __hip_bfloat16* Vt     = QKVb + 6291456;                    // [512][2048]
    __hip_bfloat16* Ab     = hsb;                               // alias: hsb dead after QKV gemm

    // prep: tables + hs->bf16 + weight transposes (one dispatch)
    prep_kernel<<<12544, 256, 0, stream>>>(hs, Wq, Wk, Wv, Wo, cosT, sinT, hsb, WqkvT, WoT);

    // fused QKV projection (64x128 tiles, 768 blocks, XCD stripe=3, depth-3 prefetch)
    gemm_pipe_kernel<1><<<768, 256, 0, stream>>>(hsb, WqkvT, QKVb, 2048, QKVN, 2048, 3);

    // RoPE (Q+K) + V transpose (one dispatch)
    ropev_kernel<<<11264, 256, 0, stream>>>(QKVb, Vt, cosT, sinT);

    // attention: 128-row blocks, 8 waves x 16 rows, writes row-major Ab directly
    attn_kernel<<<512, 512, 0, stream>>>(QKVb, QKVb + 2048, Vt, Ab);

    // output projection (64x128 tiles, 512 blocks, XCD stripe=2, depth-3 prefetch)
    gemm_pipe_kernel<0><<<512, 256, 0, stream>>>(Ab, WoT, d_out, 2048, 2048, 2048, 2);
}